// Round 7
// baseline (91.827 us; speedup 1.0000x reference)
//
#include <hip/hip_runtime.h>
#include <hip/hip_bf16.h>

// ---------- types ----------
typedef __attribute__((ext_vector_type(8))) short  short8;
typedef __attribute__((ext_vector_type(4))) float  f32x4;

#define NCLS 10
#define TILE 96            // rows per tile (3 k-slices of 32)
#define TPB  512           // 8 waves per block; 2 blocks/CU
#define NQ   10            // upper-triangular 16x16 quads of 64x64 Gram
#define PPB  (NCLS * NQ * 256)   // floats per block of partials (25600)
#define CH   16            // reduction chunks

#define AS1 __attribute__((address_space(1)))
#define AS3 __attribute__((address_space(3)))

#define MF(a, b, c) __builtin_amdgcn_mfma_f32_16x16x32_bf16((a), (b), (c), 0, 0, 0)

// fp32 -> bf16 round-to-nearest-even
static __device__ inline unsigned short f2bf(float x) {
    unsigned u = __builtin_bit_cast(unsigned, x);
    return (unsigned short)((u + 0x7FFFu + ((u >> 16) & 1u)) >> 16);
}

// ---------- DMA one tile (h fp32 + yhat) into LDS ----------
// fs layout: plain row-major [96][64] fp32. Rows >= N clamp to N-1 (data is
// finite garbage; excluded later because BOTH MFMA operands are masked).
// Per wave i-th instr: LDS base uniform, lane writes base+lane*16 (HW rule).
static __device__ __forceinline__ void issue_tile(
        const float* __restrict__ h, const int* __restrict__ yhat,
        float* fsb, int* yb, long t, long N, int wid, int lane) {
#pragma unroll
    for (int i = 0; i < 3; ++i) {
        const int C = wid * 64 + i * 512 + lane;    // 16B chunk id, 0..1535
        long row = t * TILE + (C >> 4);
        if (row > N - 1) row = N - 1;
        const float* gp = h + row * 64 + ((C & 15) << 2);
        __builtin_amdgcn_global_load_lds((const AS1 float*)gp,
                                         (AS3 float*)(fsb + (wid * 64 + i * 512) * 4),
                                         16, 0, 0);
    }
    if (wid == 0 && lane < 24) {    // 96 ints = 24 x 16B (N%4==0 holds)
        long y0 = t * TILE + lane * 4;
        if (y0 > N - 4) y0 = N - 4;
        __builtin_amdgcn_global_load_lds((const AS1 int*)(yhat + y0),
                                         (AS3 int*)yb, 16, 0, 0);
    }
}

// ---------- per-tile compute: own class (10 quads) + extra-class quad slice ----------
static __device__ __forceinline__ void compute_tile(
        const char* hsb, const unsigned short* mkb, int cls, int xcls, int wq,
        int hi, int col, f32x4 (&acc)[NQ], f32x4 (&accx)[3]) {
    const int sw = (col & 3) << 4;
#pragma unroll
    for (int ks = 0; ks < 3; ++ks) {
        const int b2 = ks * 64 + hi * 16;          // byte offset of rows krow..+7
        const short8 m = *(const short8*)((const char*)mkb + cls * 192 + b2);
        short8 raw[4], am[4];
#pragma unroll
        for (int nb = 0; nb < 4; ++nb) {
            raw[nb] = *(const short8*)(hsb + (nb * 16 + col) * 192 + (b2 ^ sw));
            am[nb]  = raw[nb] & m;
        }
        acc[0] = MF(am[0], am[0], acc[0]);
        acc[1] = MF(am[0], am[1], acc[1]);
        acc[2] = MF(am[0], am[2], acc[2]);
        acc[3] = MF(am[0], am[3], acc[3]);
        acc[4] = MF(am[1], am[1], acc[4]);
        acc[5] = MF(am[1], am[2], acc[5]);
        acc[6] = MF(am[1], am[3], acc[6]);
        acc[7] = MF(am[2], am[2], acc[7]);
        acc[8] = MF(am[2], am[3], acc[8]);
        acc[9] = MF(am[3], am[3], acc[9]);

        const short8 mx = *(const short8*)((const char*)mkb + xcls * 192 + b2);
        switch (wq) {   // static quad slices of the extra class (8 or 9)
        case 0: { short8 x0 = raw[0] & mx, x1 = raw[1] & mx;
                  accx[0] = MF(x0, x0, accx[0]);
                  accx[1] = MF(x0, x1, accx[1]);
                  accx[2] = MF(x1, x1, accx[2]); } break;
        case 1: { short8 x0 = raw[0] & mx, x2 = raw[2] & mx, x3 = raw[3] & mx;
                  accx[0] = MF(x0, x2, accx[0]);
                  accx[1] = MF(x0, x3, accx[1]); } break;
        case 2: { short8 x1 = raw[1] & mx, x2 = raw[2] & mx, x3 = raw[3] & mx;
                  accx[0] = MF(x1, x2, accx[0]);
                  accx[1] = MF(x1, x3, accx[1]);
                  accx[2] = MF(x2, x2, accx[2]); } break;
        default:{ short8 x2 = raw[2] & mx, x3 = raw[3] & mx;
                  accx[0] = MF(x2, x3, accx[0]);
                  accx[1] = MF(x3, x3, accx[1]); } break;
        }
    }
}

// ---------- kernel 1: masked Grams via MFMA; 8 waves, 2 blocks/CU ----------
// partials: [G][NCLS][NQ][256] f32; cntp: [G][16] int. Both fully overwritten.
__global__ __launch_bounds__(TPB, 4) void HL_gram(
        const float* __restrict__ h, const int* __restrict__ yhat,
        float* __restrict__ partials, int* __restrict__ cntp,
        long N, int ntiles, int G) {
    __shared__ __align__(16) float          fs[2][TILE * 64];   // 49152 B
    __shared__ __align__(16) unsigned short hs[64 * TILE];      // 12288 B, swizzled
    __shared__ __align__(16) unsigned short mk[NCLS * TILE];    // 1920 B
    __shared__ __align__(16) int            ylds[2][TILE];      // 768 B
    __shared__ int cntlds[16];                                  // 64 B  => 62.7 KB

    const int tid  = threadIdx.x;
    const int wid  = tid >> 6;      // 0..7; wave owns class wid
    const int lane = tid & 63;
    const int hi   = lane >> 4;
    const int col  = lane & 15;

    const int cls  = wid;
    const int xcls = 8 + (wid >> 2);
    const int wq   = wid & 3;

    if (tid < 16) cntlds[tid] = 0;
    __syncthreads();                // nothing in flight yet; full drain OK

    f32x4 acc[NQ], accx[3];
#pragma unroll
    for (int q = 0; q < NQ; ++q) acc[q] = (f32x4){0.f, 0.f, 0.f, 0.f};
#pragma unroll
    for (int q = 0; q < 3; ++q)  accx[q] = (f32x4){0.f, 0.f, 0.f, 0.f};

    const int bid = blockIdx.x;
    const int K   = (ntiles - bid + G - 1) / G;

    issue_tile(h, yhat, &fs[0][0], &ylds[0][0], bid, N, wid, lane);
    if (K > 1)
        issue_tile(h, yhat, &fs[1][0], &ylds[1][0], bid + (long)G, N, wid, lane);

    for (int k = 0; k < K; ++k) {
        const long t  = bid + (long)k * G;
        const int  bk = k & 1;

        // bar1: per-wave counted wait for tile k's DMA (keep tile k+1 in flight)
        if (k + 1 < K) {
            if (wid == 0) asm volatile("s_waitcnt vmcnt(4)" ::: "memory");
            else          asm volatile("s_waitcnt vmcnt(3)" ::: "memory");
        } else {
            asm volatile("s_waitcnt vmcnt(0)" ::: "memory");
        }
        __builtin_amdgcn_s_barrier();

        // ---- phase A: waves 0-5 convert fp32->bf16 swizzled; waves 6-7 masks+counts
        if (tid < 384) {
            const int d  = lane;
            const int r0 = wid * 16;
            const float* fp = &fs[bk][0] + r0 * 64 + d;   // row-uniform reads
            short8 w0, w1;
#pragma unroll
            for (int j = 0; j < 8; ++j) w0[j] = (short)f2bf(fp[j * 64]);
#pragma unroll
            for (int j = 0; j < 8; ++j) w1[j] = (short)f2bf(fp[(j + 8) * 64]);
            const int sw = (d & 3) << 4;
            char* hb = (char*)hs + d * 192;
            *(short8*)(hb + ((r0 * 2)      ^ sw)) = w0;
            *(short8*)(hb + ((r0 * 2 + 16) ^ sw)) = w1;
        } else {
            const int r = (wid - 6) * 64 + lane;   // 0..127
            if (r < TILE) {
                const long grow = t * TILE + r;
                const int y = (grow < N) ? ylds[bk][r] : -1;
#pragma unroll
                for (int c = 0; c < NCLS; ++c) {
                    mk[c * TILE + r] = (y == c) ? (unsigned short)0xFFFFu
                                                : (unsigned short)0u;
                    unsigned long long b = __ballot(y == c);
                    if (lane == 0) atomicAdd(&cntlds[c], __popcll(b));
                }
            }
        }

        asm volatile("s_waitcnt lgkmcnt(0)" ::: "memory");
        __builtin_amdgcn_s_barrier();   // bar2: hs + mk visible

        // ---- phase B: refill ring slot bk for tile k+2, then compute tile k
        if (k + 2 < K)
            issue_tile(h, yhat, &fs[bk][0], &ylds[bk][0],
                       bid + (long)(k + 2) * G, N, wid, lane);

        compute_tile((const char*)hs, mk, cls, xcls, wq, hi, col, acc, accx);
    }

    __syncthreads();   // counts settled; nothing in flight

    // ---- epilogue: stream per-wave quads + per-block counts (no merge needed)
    float* pb = partials + (size_t)bid * PPB;
    {
        float* po = pb + (size_t)cls * (NQ * 256);
#pragma unroll
        for (int q = 0; q < NQ; ++q)
            *(f32x4*)(po + q * 256 + (lane << 2)) = acc[q];
    }
    {
        float* px = pb + (size_t)xcls * (NQ * 256) + (lane << 2);
        switch (wq) {   // canonical quad indices: see compute_tile slices
        case 0: *(f32x4*)(px + 0 * 256) = accx[0];
                *(f32x4*)(px + 1 * 256) = accx[1];
                *(f32x4*)(px + 4 * 256) = accx[2]; break;
        case 1: *(f32x4*)(px + 2 * 256) = accx[0];
                *(f32x4*)(px + 3 * 256) = accx[1]; break;
        case 2: *(f32x4*)(px + 5 * 256) = accx[0];
                *(f32x4*)(px + 6 * 256) = accx[1];
                *(f32x4*)(px + 7 * 256) = accx[2]; break;
        default:*(f32x4*)(px + 8 * 256) = accx[0];
                *(f32x4*)(px + 9 * 256) = accx[1]; break;
        }
    }
    if (tid < 16) cntp[bid * 16 + tid] = cntlds[tid];
}

// ---------- kernel 2: chunked block-reduction of partials (atomic-free) ----------
// rpart: [CH][NCLS*NQ][256] f32, fully overwritten. Also zeroes out[0].
__global__ void HL_reduce(const float* __restrict__ partials, float* __restrict__ rpart,
                          float* __restrict__ out, int G, int CS) {
    const int idx = blockIdx.x * blockDim.x + threadIdx.x;
    if (blockIdx.x == 0 && threadIdx.x == 0) out[0] = 0.f;
    if (idx >= CH * NCLS * NQ * 64) return;
    const int ch = idx / (NCLS * NQ * 64);
    const int r  = idx % (NCLS * NQ * 64);
    const int cq = r >> 6;
    const int l  = r & 63;

    int b0 = ch * CS;
    int b1 = b0 + CS; if (b1 > G) b1 = G;

    f32x4 s = (f32x4){0.f, 0.f, 0.f, 0.f};
    const float* p = partials + (size_t)cq * 256 + (l << 2);
    for (int b = b0; b < b1; ++b)
        s += *reinterpret_cast<const f32x4*>(p + (size_t)b * PPB);

    *reinterpret_cast<f32x4*>(rpart + ((size_t)ch * (NCLS * NQ) + cq) * 256 + (l << 2)) = s;
}

// ---------- kernel 3: counts + M = 0.5*G/cnt + I; loss += 0.5*logdet ----------
__global__ __launch_bounds__(64, 1) void HL_chol(
        const float* __restrict__ rpart, const int* __restrict__ cntp,
        float* __restrict__ out, int G) {
    __shared__ float M[64][68];
    __shared__ float lcol[64];
    const int cls = blockIdx.x;
    const int i   = threadIdx.x;   // lane 0..63

    int c = 0;
    for (int b = i; b < G; b += 64) c += cntp[b * 16 + cls];
#pragma unroll
    for (int off = 32; off > 0; off >>= 1) c += __shfl_xor(c, off);
    const float inv = 0.5f / (float)c;

    const int QMB[NQ] = {0,0,0,0,1,1,1,2,2,3};
    const int QNB[NQ] = {0,1,2,3,1,2,3,2,3,3};
    const float* rp = rpart + (size_t)cls * (NQ * 256);
#pragma unroll
    for (int q = 0; q < NQ; ++q) {
        f32x4 s = (f32x4){0.f, 0.f, 0.f, 0.f};
#pragma unroll
        for (int ch = 0; ch < CH; ++ch)
            s += *reinterpret_cast<const f32x4*>(rp + (size_t)ch * (NCLS * NQ * 256) + q * 256 + (i << 2));
        const int row0 = QMB[q] * 16 + ((i >> 4) << 2);
        const int colo = QNB[q] * 16 + (i & 15);
#pragma unroll
        for (int rr = 0; rr < 4; ++rr) {
            M[row0 + rr][colo] = s[rr];
            M[colo][row0 + rr] = s[rr];
        }
    }
    __syncthreads();

    float row[64];
#pragma unroll
    for (int c2 = 0; c2 < 64; ++c2)
        row[c2] = M[i][c2] * inv + (c2 == i ? 1.0f : 0.0f);

#pragma unroll
    for (int j = 0; j < 64; ++j) {
        const float piv = __shfl(row[j], j);
        const float li  = row[j] * rsqrtf(piv);
        lcol[i] = li;
        __syncthreads();
#pragma unroll
        for (int c2 = j + 1; c2 < 64; ++c2)
            row[c2] -= li * lcol[c2];
        __syncthreads();
    }

    float slog = 0.f;
#pragma unroll
    for (int j = 0; j < 64; ++j)
        if (i == j) slog = __logf(row[j]);
    slog += __shfl_down(slog, 32); slog += __shfl_down(slog, 16);
    slog += __shfl_down(slog, 8);  slog += __shfl_down(slog, 4);
    slog += __shfl_down(slog, 2);  slog += __shfl_down(slog, 1);
    if (i == 0) atomicAdd(out, 0.5f * slog);
}

// ---------- launcher ----------
extern "C" void kernel_launch(void* const* d_in, const int* in_sizes, int n_in,
                              void* d_out, int out_size, void* d_ws, size_t ws_size,
                              hipStream_t stream) {
    const float* h    = (const float*)d_in[0];
    const int*   yhat = (const int*)d_in[1];
    const long   N    = in_sizes[1];
    float* out = (float*)d_out;

    // ws layout: [rpart CH*100*256 f32][cntp G*16 int][partials G*PPB f32]
    const size_t rpart_sz = (size_t)CH * NCLS * NQ * 256 * sizeof(float);
    const size_t cntp_off = rpart_sz;

    const int ntiles = (int)((N + TILE - 1) / TILE);
    int G = 512;    // 2 blocks per CU
    {
        const size_t perG = 64 + (size_t)PPB * sizeof(float);
        if (ws_size > rpart_sz) {
            size_t maxG = (ws_size - rpart_sz) / perG;
            if ((size_t)G > maxG) G = (int)maxG;
        } else G = 1;
        if (G < 1) G = 1;
    }
    if (G > ntiles) G = ntiles;

    const size_t partials_off = cntp_off + (size_t)G * 16 * sizeof(int);
    float* rpart    = (float*)d_ws;
    int*   cntp     = (int*)((char*)d_ws + cntp_off);
    float* partials = (float*)((char*)d_ws + partials_off);

    HL_gram<<<G, TPB, 0, stream>>>(h, yhat, partials, cntp, N, ntiles, G);

    int CS = (G + CH - 1) / CH;
    const int rthreads = CH * NCLS * NQ * 64;
    HL_reduce<<<(rthreads + 255) / 256, 256, 0, stream>>>(partials, rpart, out, G, CS);

    HL_chol<<<NCLS, 64, 0, stream>>>(rpart, cntp, out, G);
}

// Round 9
// 84.944 us; speedup vs baseline: 1.0810x; 1.0810x over previous
//
#include <hip/hip_runtime.h>
#include <hip/hip_bf16.h>

// ---------- types ----------
typedef __attribute__((ext_vector_type(8))) short    short8;
typedef __attribute__((ext_vector_type(4))) float    f32x4;
typedef __attribute__((ext_vector_type(4))) _Float16 f16x4;
typedef __attribute__((ext_vector_type(2))) unsigned u32x2;

#define NCLS 10
#define TILE 64            // rows per tile (2 k-slices of 32)
#define TPB  512           // 8 waves per block; 2 blocks/CU (67 KB LDS)
#define NQ   10            // upper-triangular 16x16 quads of 64x64 Gram
#define PPB  (NCLS * NQ * 256)   // halves per block of partials (25600 -> 50 KB)
#define CH   16            // reduction chunks

#define AS1 __attribute__((address_space(1)))
#define AS3 __attribute__((address_space(3)))

#define MF(a, b, c) __builtin_amdgcn_mfma_f32_16x16x32_bf16((a), (b), (c), 0, 0, 0)

static __device__ __forceinline__ unsigned pkh2(float a, float b) {
    unsigned short ha = __builtin_bit_cast(unsigned short, (_Float16)a);
    unsigned short hb = __builtin_bit_cast(unsigned short, (_Float16)b);
    return (unsigned)ha | ((unsigned)hb << 16);
}

// ---------- DMA one tile (h fp32 + yhat) into LDS, fully linear ----------
// fs: row-major [64][64] fp32 (16 KB). Rows >= N clamp to N-1 (junk data is
// excluded because BOTH MFMA operands are masked; y for those rows -> -1).
static __device__ __forceinline__ void issue_tile(
        const float* __restrict__ h, const int* __restrict__ yhat,
        float* fsb, int* yb, long t, long N, int wid, int lane) {
#pragma unroll
    for (int i = 0; i < 2; ++i) {
        const int C = (wid * 2 + i) * 64 + lane;    // 16B chunk id, 0..1023
        long row = t * TILE + (C >> 4);
        if (row > N - 1) row = N - 1;
        const float* gp = h + row * 64 + ((C & 15) << 2);
        __builtin_amdgcn_global_load_lds((const AS1 float*)gp,
                                         (AS3 float*)(fsb + (wid * 2 + i) * 256),
                                         16, 0, 0);
    }
    if (wid == 0 && lane < 16) {    // 64 ints = 16 x 16B (N%4==0 holds)
        long y0 = t * TILE + lane * 4;
        if (y0 > N - 4) y0 = N - 4;
        __builtin_amdgcn_global_load_lds((const AS1 int*)(yhat + y0),
                                         (AS3 int*)yb, 16, 0, 0);
    }
}

// ---------- compute one tile: own class (10 quads) + extra-class slice ----------
static __device__ __forceinline__ void compute_tile(
        const char* hsb, const char* mkb, int cls, int xcls, int wq,
        int hi, int col, f32x4 (&acc)[NQ], f32x4 (&accx)[3]) {
    const int sw = (col & 7) << 4;
#pragma unroll
    for (int ks = 0; ks < 2; ++ks) {
        const int b2 = ks * 64 + hi * 16;     // byte offset of rows ks*32+hi*8 ..+7
        const short8 m = *(const short8*)(mkb + cls * 128 + b2);
        short8 raw[4], am[4];
#pragma unroll
        for (int nb = 0; nb < 4; ++nb) {
            raw[nb] = *(const short8*)(hsb + (nb * 16 + col) * 128 + (b2 ^ sw));
            am[nb]  = raw[nb] & m;
        }
        acc[0] = MF(am[0], am[0], acc[0]);
        acc[1] = MF(am[0], am[1], acc[1]);
        acc[2] = MF(am[0], am[2], acc[2]);
        acc[3] = MF(am[0], am[3], acc[3]);
        acc[4] = MF(am[1], am[1], acc[4]);
        acc[5] = MF(am[1], am[2], acc[5]);
        acc[6] = MF(am[1], am[3], acc[6]);
        acc[7] = MF(am[2], am[2], acc[7]);
        acc[8] = MF(am[2], am[3], acc[8]);
        acc[9] = MF(am[3], am[3], acc[9]);

        const short8 mx = *(const short8*)(mkb + xcls * 128 + b2);
        switch (wq) {
        case 0: { short8 x0 = raw[0] & mx, x1 = raw[1] & mx;
                  accx[0] = MF(x0, x0, accx[0]);
                  accx[1] = MF(x0, x1, accx[1]);
                  accx[2] = MF(x1, x1, accx[2]); } break;
        case 1: { short8 x0 = raw[0] & mx, x2 = raw[2] & mx, x3 = raw[3] & mx;
                  accx[0] = MF(x0, x2, accx[0]);
                  accx[1] = MF(x0, x3, accx[1]); } break;
        case 2: { short8 x1 = raw[1] & mx, x2 = raw[2] & mx, x3 = raw[3] & mx;
                  accx[0] = MF(x1, x2, accx[0]);
                  accx[1] = MF(x1, x3, accx[1]);
                  accx[2] = MF(x2, x2, accx[2]); } break;
        default:{ short8 x2 = raw[2] & mx, x3 = raw[3] & mx;
                  accx[0] = MF(x2, x3, accx[0]);
                  accx[1] = MF(x3, x3, accx[1]); } break;
        }
    }
}

// ---------- kernel 1: masked Grams; 1 barrier/tile, convert(k) || compute(k-1) ----------
// partials: [G][NCLS][NQ][256] f16; cntp: [G][16] int. Both fully overwritten.
__global__ __launch_bounds__(TPB, 4) void HL_gram(
        const float* __restrict__ h, const int* __restrict__ yhat,
        _Float16* __restrict__ partials, int* __restrict__ cntp,
        long N, int ntiles, int G) {
    __shared__ __align__(16) float          fs[3][TILE * 64];    // 48 KB fp32 ring
    __shared__ __align__(16) unsigned short hs[2][64 * TILE];    // 16 KB bf16 swz
    __shared__ __align__(16) unsigned short mk[2][NCLS * TILE];  // 2.5 KB masks
    __shared__ __align__(16) int            ylds[3][TILE];       // 768 B

    const int tid  = threadIdx.x;
    const int wid  = tid >> 6;      // 0..7; wave owns class wid
    const int lane = tid & 63;
    const int hi   = lane >> 4;
    const int col  = lane & 15;

    const int cls  = wid;
    const int xcls = 8 + (wid >> 2);
    const int wq   = wid & 3;

    f32x4 acc[NQ], accx[3];
#pragma unroll
    for (int q = 0; q < NQ; ++q) acc[q] = (f32x4){0.f, 0.f, 0.f, 0.f};
#pragma unroll
    for (int q = 0; q < 3; ++q)  accx[q] = (f32x4){0.f, 0.f, 0.f, 0.f};
    int c0=0,c1=0,c2=0,c3=0,c4=0,c5=0,c6=0,c7=0,c8=0,c9=0;   // wave 7 counts

    const int bid = blockIdx.x;
    const int K   = (ntiles - bid + G - 1) / G;

    issue_tile(h, yhat, &fs[0][0], &ylds[0][0], bid, N, wid, lane);
    if (K > 1)
        issue_tile(h, yhat, &fs[1][0], &ylds[1][0], bid + (long)G, N, wid, lane);

    for (int k = 0; k < K; ++k) {
        const long t  = bid + (long)k * G;
        const int  fk = k % 3;      // fp32/y ring slot of tile k
        const int  hk = k & 1;      // bf16/mask buffer for tile k

        // ---- entry: drain DMA(t_k) keeping DMA(t_{k+1}) in flight; make
        //      phase-(k-1) LDS writes visible; single barrier per tile.
        if (k + 1 < K) {
            if (wid == 0) asm volatile("s_waitcnt vmcnt(3)" ::: "memory");
            else          asm volatile("s_waitcnt vmcnt(2)" ::: "memory");
        } else {
            asm volatile("s_waitcnt vmcnt(0)" ::: "memory");
        }
        asm volatile("s_waitcnt lgkmcnt(0)" ::: "memory");
        __builtin_amdgcn_s_barrier();
        __builtin_amdgcn_sched_barrier(0);

        // ---- convert tile k: wave w owns rows w*8..w*8+7, lane = d ----
        {
            const float* fp = &fs[fk][0] + (wid * 8) * 64 + lane;
            float x[8];
#pragma unroll
            for (int j = 0; j < 8; ++j) x[j] = fp[j * 64];   // bank d%32: 2-way free
            u32x2 lohi[2];
#pragma unroll
            for (int p = 0; p < 4; ++p) {
                __hip_bfloat162 pr = __float22bfloat162_rn(make_float2(x[2*p], x[2*p+1]));
                unsigned u;
                __builtin_memcpy(&u, &pr, 4);
                ((unsigned*)lohi)[p] = u;
            }
            char* hb = (char*)&hs[hk][0] + lane * 128 + ((wid * 16) ^ ((lane & 7) << 4));
            *(u32x2*)hb       = lohi[0];
            *(u32x2*)(hb + 8) = lohi[1];
        }
        // ---- masks + counts: wave 7, lane = row ----
        if (wid == 7) {
            int y = ylds[fk][lane];
            if (t * TILE + lane >= N) y = -1;
            unsigned short* mb = &mk[hk][0];
#pragma unroll
            for (int c = 0; c < NCLS; ++c)
                mb[c * TILE + lane] = (y == c) ? (unsigned short)0xFFFFu
                                               : (unsigned short)0u;
            c0 += (int)__popcll(__ballot(y == 0));
            c1 += (int)__popcll(__ballot(y == 1));
            c2 += (int)__popcll(__ballot(y == 2));
            c3 += (int)__popcll(__ballot(y == 3));
            c4 += (int)__popcll(__ballot(y == 4));
            c5 += (int)__popcll(__ballot(y == 5));
            c6 += (int)__popcll(__ballot(y == 6));
            c7 += (int)__popcll(__ballot(y == 7));
            c8 += (int)__popcll(__ballot(y == 8));
            c9 += (int)__popcll(__ballot(y == 9));
        }

        // ---- prefetch: DMA tile k+2 into ring slot (k+2)%3 ----
        if (k + 2 < K)
            issue_tile(h, yhat, &fs[(k + 2) % 3][0], &ylds[(k + 2) % 3][0],
                       bid + (long)(k + 2) * G, N, wid, lane);

        // ---- compute tile k-1 (hs/mk buffer hk^1) ----
        if (k > 0)
            compute_tile((const char*)&hs[hk ^ 1][0], (const char*)&mk[hk ^ 1][0],
                         cls, xcls, wq, hi, col, acc, accx);
    }

    // ---- epilogue: compute the last converted tile ----
    asm volatile("s_waitcnt lgkmcnt(0)" ::: "memory");
    __builtin_amdgcn_s_barrier();
    __builtin_amdgcn_sched_barrier(0);
    compute_tile((const char*)&hs[(K - 1) & 1][0], (const char*)&mk[(K - 1) & 1][0],
                 cls, xcls, wq, hi, col, acc, accx);

    // ---- stream partials (f16) + per-block counts ----
    _Float16* pb = partials + (size_t)bid * PPB;
    {
        _Float16* po = pb + (size_t)cls * (NQ * 256);
#pragma unroll
        for (int q = 0; q < NQ; ++q) {
            u32x2 pk; pk[0] = pkh2(acc[q][0], acc[q][1]);
            pk[1] = pkh2(acc[q][2], acc[q][3]);
            *(u32x2*)(po + q * 256 + (lane << 2)) = pk;
        }
    }
    {
        _Float16* px = pb + (size_t)xcls * (NQ * 256) + (lane << 2);
        u32x2 pk0, pk1, pk2;
        pk0[0] = pkh2(accx[0][0], accx[0][1]); pk0[1] = pkh2(accx[0][2], accx[0][3]);
        pk1[0] = pkh2(accx[1][0], accx[1][1]); pk1[1] = pkh2(accx[1][2], accx[1][3]);
        pk2[0] = pkh2(accx[2][0], accx[2][1]); pk2[1] = pkh2(accx[2][2], accx[2][3]);
        switch (wq) {
        case 0: *(u32x2*)(px + 0 * 256) = pk0;
                *(u32x2*)(px + 1 * 256) = pk1;
                *(u32x2*)(px + 4 * 256) = pk2; break;
        case 1: *(u32x2*)(px + 2 * 256) = pk0;
                *(u32x2*)(px + 3 * 256) = pk1; break;
        case 2: *(u32x2*)(px + 5 * 256) = pk0;
                *(u32x2*)(px + 6 * 256) = pk1;
                *(u32x2*)(px + 7 * 256) = pk2; break;
        default:*(u32x2*)(px + 8 * 256) = pk0;
                *(u32x2*)(px + 9 * 256) = pk1; break;
        }
    }
    if (wid == 7 && lane == 0) {
        int* cp = cntp + bid * 16;
        cp[0]=c0; cp[1]=c1; cp[2]=c2; cp[3]=c3; cp[4]=c4;
        cp[5]=c5; cp[6]=c6; cp[7]=c7; cp[8]=c8; cp[9]=c9;
    }
}

// ---------- kernel 2: chunked block-reduction of f16 partials (atomic-free) ----------
// rpart: [CH][NCLS*NQ][256] f32, fully overwritten. Also zeroes out[0].
__global__ void HL_reduce(const _Float16* __restrict__ partials, float* __restrict__ rpart,
                          float* __restrict__ out, int G, int CS) {
    const int idx = blockIdx.x * blockDim.x + threadIdx.x;
    if (blockIdx.x == 0 && threadIdx.x == 0) out[0] = 0.f;
    if (idx >= CH * NCLS * NQ * 64) return;
    const int ch = idx / (NCLS * NQ * 64);
    const int r  = idx % (NCLS * NQ * 64);
    const int cq = r >> 6;
    const int l  = r & 63;

    int b0 = ch * CS;
    int b1 = b0 + CS; if (b1 > G) b1 = G;

    f32x4 s = (f32x4){0.f, 0.f, 0.f, 0.f};
    const _Float16* p = partials + (size_t)cq * 256 + (l << 2);
    for (int b = b0; b < b1; ++b) {
        f16x4 v = *(const f16x4*)(p + (size_t)b * PPB);
        s[0] += (float)v[0]; s[1] += (float)v[1];
        s[2] += (float)v[2]; s[3] += (float)v[3];
    }
    *reinterpret_cast<f32x4*>(rpart + ((size_t)ch * (NCLS * NQ) + cq) * 256 + (l << 2)) = s;
}

// ---------- kernel 3: counts + M = 0.5*G/cnt + I; loss += 0.5*logdet ----------
__global__ __launch_bounds__(64, 1) void HL_chol(
        const float* __restrict__ rpart, const int* __restrict__ cntp,
        float* __restrict__ out, int G) {
    __shared__ float M[64][68];
    __shared__ float lcol[64];
    const int cls = blockIdx.x;
    const int i   = threadIdx.x;   // lane 0..63

    int c = 0;
    for (int b = i; b < G; b += 64) c += cntp[b * 16 + cls];
#pragma unroll
    for (int off = 32; off > 0; off >>= 1) c += __shfl_xor(c, off);
    const float inv = 0.5f / (float)c;

    const int QMB[NQ] = {0,0,0,0,1,1,1,2,2,3};
    const int QNB[NQ] = {0,1,2,3,1,2,3,2,3,3};
    const float* rp = rpart + (size_t)cls * (NQ * 256);
#pragma unroll
    for (int q = 0; q < NQ; ++q) {
        f32x4 s = (f32x4){0.f, 0.f, 0.f, 0.f};
#pragma unroll
        for (int ch = 0; ch < CH; ++ch)
            s += *reinterpret_cast<const f32x4*>(rp + (size_t)ch * (NCLS * NQ * 256) + q * 256 + (i << 2));
        const int row0 = QMB[q] * 16 + ((i >> 4) << 2);
        const int colo = QNB[q] * 16 + (i & 15);
#pragma unroll
        for (int rr = 0; rr < 4; ++rr) {
            M[row0 + rr][colo] = s[rr];
            M[colo][row0 + rr] = s[rr];
        }
    }
    __syncthreads();

    float row[64];
#pragma unroll
    for (int c2 = 0; c2 < 64; ++c2)
        row[c2] = M[i][c2] * inv + (c2 == i ? 1.0f : 0.0f);

#pragma unroll
    for (int j = 0; j < 64; ++j) {
        const float piv = __shfl(row[j], j);
        const float li  = row[j] * rsqrtf(piv);
        lcol[i] = li;
        __syncthreads();
#pragma unroll
        for (int c2 = j + 1; c2 < 64; ++c2)
            row[c2] -= li * lcol[c2];
        __syncthreads();
    }

    float slog = 0.f;
#pragma unroll
    for (int j = 0; j < 64; ++j)
        if (i == j) slog = __logf(row[j]);
    slog += __shfl_down(slog, 32); slog += __shfl_down(slog, 16);
    slog += __shfl_down(slog, 8);  slog += __shfl_down(slog, 4);
    slog += __shfl_down(slog, 2);  slog += __shfl_down(slog, 1);
    if (i == 0) atomicAdd(out, 0.5f * slog);
}

// ---------- launcher ----------
extern "C" void kernel_launch(void* const* d_in, const int* in_sizes, int n_in,
                              void* d_out, int out_size, void* d_ws, size_t ws_size,
                              hipStream_t stream) {
    const float* h    = (const float*)d_in[0];
    const int*   yhat = (const int*)d_in[1];
    const long   N    = in_sizes[1];
    float* out = (float*)d_out;

    // ws layout: [rpart CH*100*256 f32][cntp G*16 int][partials G*PPB f16]
    const size_t rpart_sz = (size_t)CH * NCLS * NQ * 256 * sizeof(float);  // 1.64 MB
    const size_t cntp_off = rpart_sz;

    const int ntiles = (int)((N + TILE - 1) / TILE);
    int G = 512;    // 2 blocks per CU
    {
        const size_t perG = 64 + (size_t)PPB * sizeof(_Float16);
        if (ws_size > rpart_sz) {
            size_t maxG = (ws_size - rpart_sz) / perG;
            if ((size_t)G > maxG) G = (int)maxG;
        } else G = 1;
        if (G < 1) G = 1;
    }
    if (G > ntiles) G = ntiles;

    const size_t partials_off = cntp_off + (size_t)G * 16 * sizeof(int);
    float*    rpart    = (float*)d_ws;
    int*      cntp     = (int*)((char*)d_ws + cntp_off);
    _Float16* partials = (_Float16*)((char*)d_ws + partials_off);

    HL_gram<<<G, TPB, 0, stream>>>(h, yhat, partials, cntp, N, ntiles, G);

    int CS = (G + CH - 1) / CH;
    const int rthreads = CH * NCLS * NQ * 64;
    HL_reduce<<<(rthreads + 255) / 256, 256, 0, stream>>>(partials, rpart, out, G, CS);

    HL_chol<<<NCLS, 64, 0, stream>>>(rpart, cntp, out, G);
}